// Round 1
// baseline (1221.758 us; speedup 1.0000x reference)
//
#include <hip/hip_runtime.h>
#include <stdint.h>
#include <math.h>

#define NN 10000
#define NE 30000
#define NG 50
#define NH 8

typedef _Float16 f16;
typedef _Float16 f16x2 __attribute__((ext_vector_type(2)));
typedef _Float16 f16x8 __attribute__((ext_vector_type(8)));
typedef float f32x4 __attribute__((ext_vector_type(4)));

// ---------------- helpers ----------------
__device__ inline void atomicMaxF(float* addr, float val) {
    if (val >= 0.0f) atomicMax((int*)addr, __float_as_int(val));
    else             atomicMin((unsigned int*)addr, __float_as_uint(val));
}

// ---------------- CSR build ----------------
__global__ void hist_kernel(const int* __restrict__ dst, int* __restrict__ deg, int E) {
    int e = blockIdx.x * blockDim.x + threadIdx.x;
    if (e < E) atomicAdd(&deg[dst[e]], 1);
}

__global__ __launch_bounds__(1024) void scan_kernel(const int* __restrict__ deg, int* __restrict__ offs, int n) {
    __shared__ int tmp[1024];
    __shared__ int carry;
    if (threadIdx.x == 0) { carry = 0; offs[0] = 0; }
    __syncthreads();
    for (int base = 0; base < n; base += 1024) {
        int i = base + (int)threadIdx.x;
        int v = (i < n) ? deg[i] : 0;
        tmp[threadIdx.x] = v;
        __syncthreads();
        for (int d = 1; d < 1024; d <<= 1) {
            int t = 0;
            if ((int)threadIdx.x >= d) t = tmp[threadIdx.x - d];
            __syncthreads();
            if ((int)threadIdx.x >= d) tmp[threadIdx.x] += t;
            __syncthreads();
        }
        if (i < n) offs[i + 1] = carry + tmp[threadIdx.x];
        __syncthreads();
        if (threadIdx.x == 0) carry += tmp[1023];
        __syncthreads();
    }
}

__global__ void copy_int(const int* __restrict__ a, int* __restrict__ b, int n) {
    int i = blockIdx.x * blockDim.x + threadIdx.x;
    if (i < n) b[i] = a[i];
}

__global__ void scatter_kernel(const int* __restrict__ dst, int* __restrict__ cursor,
                               int* __restrict__ eidx, int E) {
    int e = blockIdx.x * blockDim.x + threadIdx.x;
    if (e < E) {
        int p = atomicAdd(&cursor[dst[e]], 1);
        eidx[p] = e;
    }
}

// ---------------- conversions ----------------
__global__ void cvt_f16_kernel(const float* __restrict__ in, f16* __restrict__ out, int n) {
    int i = blockIdx.x * blockDim.x + threadIdx.x;
    if (i < n) out[i] = (f16)in[i];
}

// W is [K,N] row-major fp32; Wt is [N,K] row-major f16
__global__ void transpose_cvt_kernel(const float* __restrict__ W, f16* __restrict__ Wt, int K, int N) {
    int tid = blockIdx.x * blockDim.x + threadIdx.x;
    if (tid >= K * N) return;
    int k = tid / N;
    int n = tid - k * N;
    Wt[(size_t)n * K + k] = (f16)W[tid];
}

// ---------------- GEMM: C[M,N] = A[M,K] @ Bt[N,K]^T + bias ----------------
// wave computes 64x64 via 4x4 of 16x16x32 f16 MFMA; block = 4 waves = 256x64 tile.
template<bool OUT_F16>
__global__ __launch_bounds__(256) void gemm64(const f16* __restrict__ A, const f16* __restrict__ Bt,
                                              const float* __restrict__ bias, void* __restrict__ Cout,
                                              int M, int N, int K) {
    const int lane = threadIdx.x & 63;
    const int wave = threadIdx.x >> 6;
    const int rm = blockIdx.x * 256 + wave * 64;
    const int cn = blockIdx.y * 64;
    const int l16 = lane & 15;
    const int quad = lane >> 4;

    f32x4 acc[4][4] = {};

    for (int k0 = 0; k0 < K; k0 += 32) {
        const int kk = k0 + quad * 8;
        f16x8 av[4], bv[4];
#pragma unroll
        for (int i = 0; i < 4; ++i) {
            int row = rm + i * 16 + l16;
            if (row >= M) row = 0;  // clamp; result rows >= M never stored
            av[i] = *(const f16x8*)(A + (size_t)row * K + kk);
        }
#pragma unroll
        for (int j = 0; j < 4; ++j) {
            int col = cn + j * 16 + l16;
            bv[j] = *(const f16x8*)(Bt + (size_t)col * K + kk);
        }
#pragma unroll
        for (int i = 0; i < 4; ++i)
#pragma unroll
            for (int j = 0; j < 4; ++j)
                acc[i][j] = __builtin_amdgcn_mfma_f32_16x16x32_f16(av[i], bv[j], acc[i][j], 0, 0, 0);
    }

#pragma unroll
    for (int j = 0; j < 4; ++j) {
        const int col = cn + j * 16 + l16;
        const float bb = bias[col];
#pragma unroll
        for (int i = 0; i < 4; ++i) {
#pragma unroll
            for (int r = 0; r < 4; ++r) {
                int row = rm + i * 16 + quad * 4 + r;
                if (row < M) {
                    float val = acc[i][j][r] + bb;
                    if (OUT_F16) ((f16*)Cout)[(size_t)row * N + col] = (f16)val;
                    else         ((float*)Cout)[(size_t)row * N + col] = val;
                }
            }
        }
    }
}

// ---------------- edge attention logits ----------------
// one wave per edge; alpha[e,h] = (1/sqrt(C)) * dot(Q[dst[e],h,:], K[src[e],h,:])
__global__ __launch_bounds__(256) void alpha_kernel(const f16* __restrict__ Q, const f16* __restrict__ Kh,
                                                    const int* __restrict__ src, const int* __restrict__ dst,
                                                    float* __restrict__ alpha, int E, int hc, int C, float scale) {
    const int wid = blockIdx.x * 4 + ((int)threadIdx.x >> 6);
    const int lane = threadIdx.x & 63;
    if (wid >= E) return;
    const int s = src[wid], d = dst[wid];
    const unsigned int* Q2 = (const unsigned int*)(Q + (size_t)d * hc);
    const unsigned int* K2 = (const unsigned int*)(Kh + (size_t)s * hc);
    const int half = C >> 1;
    for (int h = 0; h < NH; ++h) {
        float acc = 0.0f;
        const int base = (h * C) >> 1;
        for (int c = lane; c < half; c += 64) {
            f16x2 qv = __builtin_bit_cast(f16x2, Q2[base + c]);
            f16x2 kv = __builtin_bit_cast(f16x2, K2[base + c]);
            acc += (float)qv.x * (float)kv.x + (float)qv.y * (float)kv.y;
        }
#pragma unroll
        for (int o = 32; o > 0; o >>= 1) acc += __shfl_down(acc, o, 64);
        if (lane == 0) alpha[(size_t)wid * NH + h] = acc * scale;
    }
}

// ---------------- per-node softmax + aggregation + skip + ELU ----------------
// block per destination node. out[n,c] = elu( (1/H) * sum_h sum_e (ex/den) * V[src,h,c] + S[n,c] )
__global__ __launch_bounds__(256) void node_pass(const float* __restrict__ alpha, const f16* __restrict__ V,
                                                 const float* __restrict__ S, const int* __restrict__ offs,
                                                 const int* __restrict__ eidx, const int* __restrict__ srcArr,
                                                 float* __restrict__ hout, f16* __restrict__ houth,
                                                 int C, int hc) {
    const int n = blockIdx.x;
    const int e0 = offs[n];
    int d = offs[n + 1] - e0;
    if (d > 256) d = 256;

    __shared__ float sew[256 * NH];
    __shared__ int sed[256];
    const int tid = threadIdx.x;

    for (int e = tid; e < d; e += 256) sed[e] = srcArr[eidx[e0 + e]];
    if (tid < NH) {
        const int h = tid;
        float m = -3.0e38f;
        for (int e = 0; e < d; ++e) {
            float a = alpha[(size_t)eidx[e0 + e] * NH + h];
            m = fmaxf(m, a);
        }
        float den = 0.0f;
        for (int e = 0; e < d; ++e) {
            float a = alpha[(size_t)eidx[e0 + e] * NH + h];
            float ex = __expf(a - m);
            sew[e * NH + h] = ex;
            den += ex;
        }
        float inv = 1.0f / (fmaxf(den, 1e-16f) * (float)NH);
        for (int e = 0; e < d; ++e) sew[e * NH + h] *= inv;
    }
    __syncthreads();

    const int half = C >> 1;
    for (int cp = tid; cp < half; cp += 256) {
        const int c = cp * 2;
        float a0 = 0.0f, a1 = 0.0f;
        for (int e = 0; e < d; ++e) {
            const int s = sed[e];
            const unsigned int* vp = (const unsigned int*)(V + (size_t)s * hc);
#pragma unroll
            for (int h = 0; h < NH; ++h) {
                float w = sew[e * NH + h];
                f16x2 vv = __builtin_bit_cast(f16x2, vp[((h * C) >> 1) + cp]);
                a0 += w * (float)vv.x;
                a1 += w * (float)vv.y;
            }
        }
        float o0 = a0 + S[(size_t)n * C + c];
        float o1 = a1 + S[(size_t)n * C + c + 1];
        o0 = o0 > 0.0f ? o0 : (__expf(o0) - 1.0f);
        o1 = o1 > 0.0f ? o1 : (__expf(o1) - 1.0f);
        hout[(size_t)n * C + c] = o0;
        hout[(size_t)n * C + c + 1] = o1;
        houth[(size_t)n * C + c] = (f16)o0;
        houth[(size_t)n * C + c + 1] = (f16)o1;
    }
}

// ---------------- pooling ----------------
__global__ void pool_init(float* __restrict__ gm, float* __restrict__ gd, float* __restrict__ pooled) {
    int i = blockIdx.x * blockDim.x + threadIdx.x;
    if (i < NG * 64) pooled[i] = 0.0f;
    if (i < NG) { gm[i] = __int_as_float(0xff800000); gd[i] = 0.0f; }
}

// wave per node: gate value + per-graph max
__global__ __launch_bounds__(256) void gate_kernel(const float* __restrict__ h, const float* __restrict__ gw,
                                                   const float* __restrict__ gb, const int* __restrict__ batch,
                                                   float* __restrict__ g, float* __restrict__ gm, int N) {
    const int wid = blockIdx.x * 4 + ((int)threadIdx.x >> 6);
    const int lane = threadIdx.x & 63;
    if (wid >= N) return;
    float acc = h[(size_t)wid * 64 + lane] * gw[lane];
#pragma unroll
    for (int o = 32; o > 0; o >>= 1) acc += __shfl_down(acc, o, 64);
    if (lane == 0) {
        float gv = acc + gb[0];
        g[wid] = gv;
        atomicMaxF(&gm[batch[wid]], gv);
    }
}

__global__ void gate_norm(float* __restrict__ g, const float* __restrict__ gm, float* __restrict__ gd,
                          const int* __restrict__ batch, int N) {
    int n = blockIdx.x * blockDim.x + threadIdx.x;
    if (n < N) {
        int b = batch[n];
        float ge = __expf(g[n] - gm[b]);
        g[n] = ge;
        atomicAdd(&gd[b], ge);
    }
}

__global__ void pool_accum(const float* __restrict__ g, const float* __restrict__ gd,
                           const float* __restrict__ h, const int* __restrict__ batch,
                           float* __restrict__ pooled, int N) {
    int tid = blockIdx.x * blockDim.x + threadIdx.x;
    if (tid < N * 64) {
        int n = tid >> 6;
        int c = tid & 63;
        int b = batch[n];
        float w = g[n] / fmaxf(gd[b], 1e-16f);
        atomicAdd(&pooled[b * 64 + c], w * h[(size_t)n * 64 + c]);
    }
}

__global__ __launch_bounds__(512) void final_fc(const float* __restrict__ pooled, const float* __restrict__ fcw,
                                                const float* __restrict__ fcb, float* __restrict__ out) {
    int tid = threadIdx.x;
    if (tid < NG * 10) {
        int gi = tid / 10, o = tid - gi * 10;
        float acc = fcb[o];
#pragma unroll
        for (int c = 0; c < 64; ++c) acc += pooled[gi * 64 + c] * fcw[c * 10 + o];
        out[tid] = acc;
    }
}

// ---------------- host ----------------
extern "C" void kernel_launch(void* const* d_in, const int* in_sizes, int n_in,
                              void* d_out, int out_size, void* d_ws, size_t ws_size,
                              hipStream_t stream) {
    const float* x   = (const float*)d_in[0];
    const int* ei    = (const int*)d_in[1];
    const int* src   = ei;
    const int* dst   = ei + NE;
    const int* batch = (const int*)d_in[2];

    struct LayerW { int fin, C, hc; const float *qw,*qb,*kw,*kb,*vw,*vb,*sw,*sb; };
    LayerW LW[3];
    int fins[3] = {128, 512, 256};
    int Cs[3]   = {512, 256, 64};
    for (int l = 0; l < 3; ++l) {
        int b = 3 + 8 * l;
        LW[l].fin = fins[l]; LW[l].C = Cs[l]; LW[l].hc = Cs[l] * NH;
        LW[l].qw = (const float*)d_in[b + 0]; LW[l].qb = (const float*)d_in[b + 1];
        LW[l].kw = (const float*)d_in[b + 2]; LW[l].kb = (const float*)d_in[b + 3];
        LW[l].vw = (const float*)d_in[b + 4]; LW[l].vb = (const float*)d_in[b + 5];
        LW[l].sw = (const float*)d_in[b + 6]; LW[l].sb = (const float*)d_in[b + 7];
    }
    const float* gate_w = (const float*)d_in[27];
    const float* gate_b = (const float*)d_in[28];
    const float* fc_w   = (const float*)d_in[29];
    const float* fc_b   = (const float*)d_in[30];

    // workspace carve
    size_t off = 0;
    char* ws = (char*)d_ws;
    auto alloc = [&](size_t bytes) -> void* {
        void* p = ws + off;
        off = (off + bytes + 255) & ~(size_t)255;
        return p;
    };
    f16* wqt[3]; f16* wkt[3]; f16* wvt[3]; f16* wst[3];
    for (int l = 0; l < 3; ++l) {
        size_t qkv = (size_t)LW[l].fin * LW[l].hc * sizeof(f16);
        wqt[l] = (f16*)alloc(qkv);
        wkt[l] = (f16*)alloc(qkv);
        wvt[l] = (f16*)alloc(qkv);
        wst[l] = (f16*)alloc((size_t)LW[l].fin * LW[l].C * sizeof(f16));
    }
    f16* xh     = (f16*)alloc((size_t)NN * 512 * sizeof(f16));
    f16* bufA   = (f16*)alloc((size_t)NN * 4096 * sizeof(f16));   // Q, then V
    f16* bufB   = (f16*)alloc((size_t)NN * 4096 * sizeof(f16));   // K
    float* Sf   = (float*)alloc((size_t)NN * 512 * sizeof(float));
    float* hf   = (float*)alloc((size_t)NN * 512 * sizeof(float));
    float* alphaBuf = (float*)alloc((size_t)NE * NH * sizeof(float));
    int* deg    = (int*)alloc(NN * sizeof(int));
    int* offs   = (int*)alloc((NN + 1) * sizeof(int));
    int* cursor = (int*)alloc(NN * sizeof(int));
    int* eidx   = (int*)alloc(NE * sizeof(int));
    float* gbuf = (float*)alloc(NN * sizeof(float));
    float* gm   = (float*)alloc(NG * sizeof(float));
    float* gd   = (float*)alloc(NG * sizeof(float));
    float* pooled = (float*)alloc(NG * 64 * sizeof(float));
    if (off > ws_size) return;  // workspace insufficient — fail loudly (wrong output)

    // CSR build
    hipMemsetAsync(deg, 0, NN * sizeof(int), stream);
    hist_kernel<<<(NE + 255) / 256, 256, 0, stream>>>(dst, deg, NE);
    scan_kernel<<<1, 1024, 0, stream>>>(deg, offs, NN);
    copy_int<<<(NN + 255) / 256, 256, 0, stream>>>(offs, cursor, NN);
    scatter_kernel<<<(NE + 255) / 256, 256, 0, stream>>>(dst, cursor, eidx, NE);

    // weight conversion (transposed to [N,K] f16)
    for (int l = 0; l < 3; ++l) {
        int nqkv = LW[l].fin * LW[l].hc;
        transpose_cvt_kernel<<<(nqkv + 255) / 256, 256, 0, stream>>>(LW[l].qw, wqt[l], LW[l].fin, LW[l].hc);
        transpose_cvt_kernel<<<(nqkv + 255) / 256, 256, 0, stream>>>(LW[l].kw, wkt[l], LW[l].fin, LW[l].hc);
        transpose_cvt_kernel<<<(nqkv + 255) / 256, 256, 0, stream>>>(LW[l].vw, wvt[l], LW[l].fin, LW[l].hc);
        int ns = LW[l].fin * LW[l].C;
        transpose_cvt_kernel<<<(ns + 255) / 256, 256, 0, stream>>>(LW[l].sw, wst[l], LW[l].fin, LW[l].C);
    }

    // x -> f16
    cvt_f16_kernel<<<(NN * 128 + 255) / 256, 256, 0, stream>>>(x, xh, NN * 128);

    const int grid_m = (NN + 255) / 256;
    for (int l = 0; l < 3; ++l) {
        const int fin = LW[l].fin, C = LW[l].C, hc = LW[l].hc;
        dim3 gq(grid_m, hc / 64), gs(grid_m, C / 64);
        gemm64<true ><<<gq, 256, 0, stream>>>(xh, wqt[l], LW[l].qb, bufA, NN, hc, fin);
        gemm64<true ><<<gq, 256, 0, stream>>>(xh, wkt[l], LW[l].kb, bufB, NN, hc, fin);
        gemm64<false><<<gs, 256, 0, stream>>>(xh, wst[l], LW[l].sb, Sf, NN, C, fin);
        alpha_kernel<<<(NE + 3) / 4, 256, 0, stream>>>(bufA, bufB, src, dst, alphaBuf, NE, hc, C,
                                                       1.0f / sqrtf((float)C));
        gemm64<true ><<<gq, 256, 0, stream>>>(xh, wvt[l], LW[l].vb, bufA, NN, hc, fin);  // V over Q buffer
        node_pass<<<NN, 256, 0, stream>>>(alphaBuf, bufA, Sf, offs, eidx, src, hf, xh, C, hc);
    }

    // pooling
    pool_init<<<(NG * 64 + 255) / 256, 256, 0, stream>>>(gm, gd, pooled);
    gate_kernel<<<(NN + 3) / 4, 256, 0, stream>>>(hf, gate_w, gate_b, batch, gbuf, gm, NN);
    gate_norm<<<(NN + 255) / 256, 256, 0, stream>>>(gbuf, gm, gd, batch, NN);
    pool_accum<<<(NN * 64 + 255) / 256, 256, 0, stream>>>(gbuf, gd, hf, batch, pooled, NN);
    final_fc<<<1, 512, 0, stream>>>(pooled, fc_w, fc_b, (float*)d_out);
}

// Round 2
// 894.096 us; speedup vs baseline: 1.3665x; 1.3665x over previous
//
#include <hip/hip_runtime.h>
#include <stdint.h>
#include <math.h>

#define NN 10000
#define NE 30000
#define NG 50
#define NH 8

typedef _Float16 f16;
typedef _Float16 f16x2 __attribute__((ext_vector_type(2)));
typedef _Float16 f16x4 __attribute__((ext_vector_type(4)));
typedef _Float16 f16x8 __attribute__((ext_vector_type(8)));
typedef float f32x4 __attribute__((ext_vector_type(4)));

// ---------------- helpers ----------------
__device__ inline void atomicMaxF(float* addr, float val) {
    if (val >= 0.0f) atomicMax((int*)addr, __float_as_int(val));
    else             atomicMin((unsigned int*)addr, __float_as_uint(val));
}

__device__ inline void async16(f16* l, const f16* g) {
    __builtin_amdgcn_global_load_lds((const __attribute__((address_space(1))) void*)g,
                                     (__attribute__((address_space(3))) void*)l, 16, 0, 0);
}

// ---------------- CSR build ----------------
__global__ void hist_kernel(const int* __restrict__ dst, int* __restrict__ deg, int E) {
    int e = blockIdx.x * blockDim.x + threadIdx.x;
    if (e < E) atomicAdd(&deg[dst[e]], 1);
}

__global__ __launch_bounds__(1024) void scan_kernel(const int* __restrict__ deg, int* __restrict__ offs, int n) {
    __shared__ int tmp[1024];
    __shared__ int carry;
    if (threadIdx.x == 0) { carry = 0; offs[0] = 0; }
    __syncthreads();
    for (int base = 0; base < n; base += 1024) {
        int i = base + (int)threadIdx.x;
        int v = (i < n) ? deg[i] : 0;
        tmp[threadIdx.x] = v;
        __syncthreads();
        for (int d = 1; d < 1024; d <<= 1) {
            int t = 0;
            if ((int)threadIdx.x >= d) t = tmp[threadIdx.x - d];
            __syncthreads();
            if ((int)threadIdx.x >= d) tmp[threadIdx.x] += t;
            __syncthreads();
        }
        if (i < n) offs[i + 1] = carry + tmp[threadIdx.x];
        __syncthreads();
        if (threadIdx.x == 0) carry += tmp[1023];
        __syncthreads();
    }
}

__global__ void copy_int(const int* __restrict__ a, int* __restrict__ b, int n) {
    int i = blockIdx.x * blockDim.x + threadIdx.x;
    if (i < n) b[i] = a[i];
}

__global__ void scatter_kernel(const int* __restrict__ dst, int* __restrict__ cursor,
                               int* __restrict__ eidx, int E) {
    int e = blockIdx.x * blockDim.x + threadIdx.x;
    if (e < E) {
        int p = atomicAdd(&cursor[dst[e]], 1);
        eidx[p] = e;
    }
}

// ---------------- conversions / weight prep ----------------
__global__ void cvt_f16_kernel(const float* __restrict__ in, f16* __restrict__ out, int n) {
    int i = blockIdx.x * blockDim.x + threadIdx.x;
    if (i < n) out[i] = (f16)in[i];
}

// Build Bt [Ntot][K] f16 (transposed, concatenated W0|W1|zero-pad) + bias [Ntot] f32.
// W0 is [K,n0] row-major, W1 is [K,n1] row-major.
__global__ void prep2(const float* __restrict__ W0, const float* __restrict__ b0, int n0,
                      const float* __restrict__ W1, const float* __restrict__ b1, int n1,
                      f16* __restrict__ Bt, float* __restrict__ bias,
                      int K, int kshift, int Ntot) {
    int tid = blockIdx.x * blockDim.x + threadIdx.x;
    if (tid >= (Ntot << kshift)) return;
    int n = tid >> kshift;
    int k = tid & (K - 1);
    float w = 0.0f;
    if (n < n0) w = W0[(size_t)k * n0 + n];
    else if (n < n0 + n1) w = W1[(size_t)k * n1 + (n - n0)];
    Bt[tid] = (f16)w;  // tid == n*K + k
    if (k == 0) bias[n] = (n < n0) ? b0[n] : ((n < n0 + n1) ? b1[n - n0] : 0.0f);
}

// ---------------- GEMM: C[M,Np] = A[M,K] @ Bt[Np,K]^T + bias, f16 out ----------------
// m97 structure: 128x128 block tile (4 waves, 2x2 of 64x64), BK=32,
// global_load_lds width-16 staging, ds_read_b128 fragments, swapped-operand MFMA
// so each lane holds 4 consecutive output columns (packed f16x4 stores).
__global__ __launch_bounds__(256) void gemm128(const f16* __restrict__ A, const f16* __restrict__ Bt,
                                               const float* __restrict__ bias, f16* __restrict__ C,
                                               int M, int Np, int K) {
    __shared__ f16 sA[128 * 32];
    __shared__ f16 sB[128 * 32];
    const int tid  = threadIdx.x;
    const int lane = tid & 63;
    const int wave = tid >> 6;
    const int l16  = lane & 15;
    const int quad = lane >> 4;
    const int rm   = blockIdx.x * 128;
    const int cn   = blockIdx.y * 128;
    const int wrow = (wave >> 1) * 64;
    const int wcol = (wave & 1) * 64;

    // staging: chunk c (0..511): row=c>>2, kchunk=(c&3)*8 f16; thread handles c=tid, c=tid+256
    const int rA  = tid >> 2;
    const int kc  = (tid & 3) * 8;
    int rowA0 = rm + rA;       if (rowA0 >= M) rowA0 = M - 1;
    int rowA1 = rm + rA + 64;  if (rowA1 >= M) rowA1 = M - 1;
    const f16* gA0 = A + (size_t)rowA0 * K + kc;
    const f16* gA1 = A + (size_t)rowA1 * K + kc;
    const f16* gB0 = Bt + (size_t)(cn + rA) * K + kc;
    const f16* gB1 = Bt + (size_t)(cn + rA + 64) * K + kc;
    f16* lA0 = sA + tid * 8;
    f16* lA1 = sA + tid * 8 + 2048;
    f16* lB0 = sB + tid * 8;
    f16* lB1 = sB + tid * 8 + 2048;

    const f16* rdA = sA + (wrow + l16) * 32 + quad * 8;
    const f16* rdB = sB + (wcol + l16) * 32 + quad * 8;

    f32x4 acc[4][4] = {};

    for (int k0 = 0; k0 < K; k0 += 32) {
        __syncthreads();  // previous iter's ds_reads done before overwrite
        async16(lA0, gA0); async16(lA1, gA1);
        async16(lB0, gB0); async16(lB1, gB1);
        gA0 += 32; gA1 += 32; gB0 += 32; gB1 += 32;
        __syncthreads();  // drains vmcnt -> staging complete
        f16x8 av[4], bv[4];
#pragma unroll
        for (int i = 0; i < 4; ++i) av[i] = *(const f16x8*)(rdA + i * 16 * 32);
#pragma unroll
        for (int j = 0; j < 4; ++j) bv[j] = *(const f16x8*)(rdB + j * 16 * 32);
#pragma unroll
        for (int i = 0; i < 4; ++i)
#pragma unroll
            for (int j = 0; j < 4; ++j)
                // swapped operands: D[m=col][n=row]; lane -> row=l16(+16i), cols=quad*4+r(+16j)
                acc[i][j] = __builtin_amdgcn_mfma_f32_16x16x32_f16(bv[j], av[i], acc[i][j], 0, 0, 0);
    }

#pragma unroll
    for (int j = 0; j < 4; ++j) {
        const int cb = cn + wcol + j * 16 + quad * 4;
        const float4 bb = *(const float4*)(bias + cb);
#pragma unroll
        for (int i = 0; i < 4; ++i) {
            const int row = rm + wrow + i * 16 + l16;
            if (row < M) {
                f16x4 o;
                o[0] = (f16)(acc[i][j][0] + bb.x);
                o[1] = (f16)(acc[i][j][1] + bb.y);
                o[2] = (f16)(acc[i][j][2] + bb.z);
                o[3] = (f16)(acc[i][j][3] + bb.w);
                *(f16x4*)(C + (size_t)row * Np + cb) = o;
            }
        }
    }
}

// ---------------- edge attention logits ----------------
// one wave per edge; alpha[e,h] = scale * dot(Q[dst[e],h,:], K[src[e],h,:])
// Q at QK + node*stride, K at QK + node*stride + koff
__global__ __launch_bounds__(256) void alpha_kernel(const f16* __restrict__ QK,
                                                    const int* __restrict__ src, const int* __restrict__ dst,
                                                    float* __restrict__ alpha, int E, int stride, int koff,
                                                    int C, float scale) {
    const int wid = blockIdx.x * 4 + ((int)threadIdx.x >> 6);
    const int lane = threadIdx.x & 63;
    if (wid >= E) return;
    const int s = src[wid], d = dst[wid];
    const unsigned int* Q2 = (const unsigned int*)(QK + (size_t)d * stride);
    const unsigned int* K2 = (const unsigned int*)(QK + (size_t)s * stride + koff);
    const int half = C >> 1;
    for (int h = 0; h < NH; ++h) {
        float acc = 0.0f;
        const int base = (h * C) >> 1;
        for (int c = lane; c < half; c += 64) {
            f16x2 qv = __builtin_bit_cast(f16x2, Q2[base + c]);
            f16x2 kv = __builtin_bit_cast(f16x2, K2[base + c]);
            acc += (float)qv.x * (float)kv.x + (float)qv.y * (float)kv.y;
        }
#pragma unroll
        for (int o = 32; o > 0; o >>= 1) acc += __shfl_down(acc, o, 64);
        if (lane == 0) alpha[(size_t)wid * NH + h] = acc * scale;
    }
}

// ---------------- per-node softmax + aggregation + skip + ELU ----------------
// V at VS + node*Np + [0,hc), S at VS + node*Np + hc + [0,C)
__global__ __launch_bounds__(256) void node_pass(const float* __restrict__ alpha, const f16* __restrict__ VS,
                                                 const int* __restrict__ offs, const int* __restrict__ eidx,
                                                 const int* __restrict__ srcArr,
                                                 float* __restrict__ hout, f16* __restrict__ houth,
                                                 int C, int hc, int Np) {
    const int n = blockIdx.x;
    const int e0 = offs[n];
    int d = offs[n + 1] - e0;
    if (d > 256) d = 256;

    __shared__ float sew[256 * NH];
    __shared__ int sed[256];
    const int tid = threadIdx.x;

    for (int e = tid; e < d; e += 256) sed[e] = srcArr[eidx[e0 + e]];
    if (tid < NH) {
        const int h = tid;
        float m = -3.0e38f;
        for (int e = 0; e < d; ++e) {
            float a = alpha[(size_t)eidx[e0 + e] * NH + h];
            m = fmaxf(m, a);
        }
        float den = 0.0f;
        for (int e = 0; e < d; ++e) {
            float a = alpha[(size_t)eidx[e0 + e] * NH + h];
            float ex = __expf(a - m);
            sew[e * NH + h] = ex;
            den += ex;
        }
        float inv = 1.0f / (fmaxf(den, 1e-16f) * (float)NH);
        for (int e = 0; e < d; ++e) sew[e * NH + h] *= inv;
    }
    __syncthreads();

    const int half = C >> 1;
    for (int cp = tid; cp < half; cp += 256) {
        const int c = cp * 2;
        float a0 = 0.0f, a1 = 0.0f;
        for (int e = 0; e < d; ++e) {
            const int s = sed[e];
            const unsigned int* vp = (const unsigned int*)(VS + (size_t)s * Np);
#pragma unroll
            for (int h = 0; h < NH; ++h) {
                float w = sew[e * NH + h];
                f16x2 vv = __builtin_bit_cast(f16x2, vp[((h * C) >> 1) + cp]);
                a0 += w * (float)vv.x;
                a1 += w * (float)vv.y;
            }
        }
        const f16* Sp = VS + (size_t)n * Np + hc;
        float o0 = a0 + (float)Sp[c];
        float o1 = a1 + (float)Sp[c + 1];
        o0 = o0 > 0.0f ? o0 : (__expf(o0) - 1.0f);
        o1 = o1 > 0.0f ? o1 : (__expf(o1) - 1.0f);
        hout[(size_t)n * C + c] = o0;
        hout[(size_t)n * C + c + 1] = o1;
        houth[(size_t)n * C + c] = (f16)o0;
        houth[(size_t)n * C + c + 1] = (f16)o1;
    }
}

// ---------------- pooling ----------------
__global__ void pool_init(float* __restrict__ gm, float* __restrict__ gd, float* __restrict__ pooled) {
    int i = blockIdx.x * blockDim.x + threadIdx.x;
    if (i < NG * 64) pooled[i] = 0.0f;
    if (i < NG) { gm[i] = __int_as_float(0xff800000); gd[i] = 0.0f; }
}

__global__ __launch_bounds__(256) void gate_kernel(const float* __restrict__ h, const float* __restrict__ gw,
                                                   const float* __restrict__ gb, const int* __restrict__ batch,
                                                   float* __restrict__ g, float* __restrict__ gm, int N) {
    const int wid = blockIdx.x * 4 + ((int)threadIdx.x >> 6);
    const int lane = threadIdx.x & 63;
    if (wid >= N) return;
    float acc = h[(size_t)wid * 64 + lane] * gw[lane];
#pragma unroll
    for (int o = 32; o > 0; o >>= 1) acc += __shfl_down(acc, o, 64);
    if (lane == 0) {
        float gv = acc + gb[0];
        g[wid] = gv;
        atomicMaxF(&gm[batch[wid]], gv);
    }
}

__global__ void gate_norm(float* __restrict__ g, const float* __restrict__ gm, float* __restrict__ gd,
                          const int* __restrict__ batch, int N) {
    int n = blockIdx.x * blockDim.x + threadIdx.x;
    if (n < N) {
        int b = batch[n];
        float ge = __expf(g[n] - gm[b]);
        g[n] = ge;
        atomicAdd(&gd[b], ge);
    }
}

__global__ void pool_accum(const float* __restrict__ g, const float* __restrict__ gd,
                           const float* __restrict__ h, const int* __restrict__ batch,
                           float* __restrict__ pooled, int N) {
    int tid = blockIdx.x * blockDim.x + threadIdx.x;
    if (tid < N * 64) {
        int n = tid >> 6;
        int c = tid & 63;
        int b = batch[n];
        float w = g[n] / fmaxf(gd[b], 1e-16f);
        atomicAdd(&pooled[b * 64 + c], w * h[(size_t)n * 64 + c]);
    }
}

__global__ __launch_bounds__(512) void final_fc(const float* __restrict__ pooled, const float* __restrict__ fcw,
                                                const float* __restrict__ fcb, float* __restrict__ out) {
    int tid = threadIdx.x;
    if (tid < NG * 10) {
        int gi = tid / 10, o = tid - gi * 10;
        float acc = fcb[o];
#pragma unroll
        for (int c = 0; c < 64; ++c) acc += pooled[gi * 64 + c] * fcw[c * 10 + o];
        out[tid] = acc;
    }
}

// ---------------- host ----------------
extern "C" void kernel_launch(void* const* d_in, const int* in_sizes, int n_in,
                              void* d_out, int out_size, void* d_ws, size_t ws_size,
                              hipStream_t stream) {
    const float* x   = (const float*)d_in[0];
    const int* ei    = (const int*)d_in[1];
    const int* src   = ei;
    const int* dst   = ei + NE;
    const int* batch = (const int*)d_in[2];

    struct LayerW { int fin, C, hc; const float *qw,*qb,*kw,*kb,*vw,*vb,*sw,*sb; };
    LayerW LW[3];
    const int fins[3]   = {128, 512, 256};
    const int kshift[3] = {7, 9, 8};
    const int Cs[3]     = {512, 256, 64};
    const int NpVS[3]   = {4608, 2304, 640};  // hc + C padded to x128
    for (int l = 0; l < 3; ++l) {
        int b = 3 + 8 * l;
        LW[l].fin = fins[l]; LW[l].C = Cs[l]; LW[l].hc = Cs[l] * NH;
        LW[l].qw = (const float*)d_in[b + 0]; LW[l].qb = (const float*)d_in[b + 1];
        LW[l].kw = (const float*)d_in[b + 2]; LW[l].kb = (const float*)d_in[b + 3];
        LW[l].vw = (const float*)d_in[b + 4]; LW[l].vb = (const float*)d_in[b + 5];
        LW[l].sw = (const float*)d_in[b + 6]; LW[l].sb = (const float*)d_in[b + 7];
    }
    const float* gate_w = (const float*)d_in[27];
    const float* gate_b = (const float*)d_in[28];
    const float* fc_w   = (const float*)d_in[29];
    const float* fc_b   = (const float*)d_in[30];

    // workspace carve
    size_t off = 0;
    char* ws = (char*)d_ws;
    auto alloc = [&](size_t bytes) -> void* {
        void* p = ws + off;
        off = (off + bytes + 255) & ~(size_t)255;
        return p;
    };
    f16* BtQK   = (f16*)alloc((size_t)4096 * 512 * sizeof(f16));   // max 2M elems
    f16* BtVS   = (f16*)alloc((size_t)2304 * 512 * sizeof(f16));
    float* biasQK = (float*)alloc(8192 * sizeof(float));
    float* biasVS = (float*)alloc(4608 * sizeof(float));
    f16* QKVS   = (f16*)alloc((size_t)NN * 8192 * sizeof(f16));    // QK then VS (reused)
    f16* xh     = (f16*)alloc((size_t)NN * 128 * sizeof(f16));
    f16* houth  = (f16*)alloc((size_t)NN * 512 * sizeof(f16));
    float* hf   = (float*)alloc((size_t)NN * 512 * sizeof(float));
    float* alphaBuf = (float*)alloc((size_t)NE * NH * sizeof(float));
    int* deg    = (int*)alloc(NN * sizeof(int));
    int* offs   = (int*)alloc((NN + 1) * sizeof(int));
    int* cursor = (int*)alloc(NN * sizeof(int));
    int* eidx   = (int*)alloc(NE * sizeof(int));
    float* gbuf = (float*)alloc(NN * sizeof(float));
    float* gm   = (float*)alloc(NG * sizeof(float));
    float* gd   = (float*)alloc(NG * sizeof(float));
    float* pooled = (float*)alloc(NG * 64 * sizeof(float));
    if (off > ws_size) return;  // insufficient workspace -> fail loudly

    // CSR build
    hipMemsetAsync(deg, 0, NN * sizeof(int), stream);
    hist_kernel<<<(NE + 255) / 256, 256, 0, stream>>>(dst, deg, NE);
    scan_kernel<<<1, 1024, 0, stream>>>(deg, offs, NN);
    copy_int<<<(NN + 255) / 256, 256, 0, stream>>>(offs, cursor, NN);
    scatter_kernel<<<(NE + 255) / 256, 256, 0, stream>>>(dst, cursor, eidx, NE);

    // x -> f16
    cvt_f16_kernel<<<(NN * 128 + 255) / 256, 256, 0, stream>>>(x, xh, NN * 128);

    const int grid_m = (NN + 127) / 128;  // 79
    const f16* Acur = xh;
    for (int l = 0; l < 3; ++l) {
        const int K = LW[l].fin, C = LW[l].C, hc = LW[l].hc;
        const int Np0 = 2 * hc, Np1 = NpVS[l];

        // Q|K weights
        {
            int tot = Np0 << kshift[l];
            prep2<<<(tot + 255) / 256, 256, 0, stream>>>(LW[l].qw, LW[l].qb, hc,
                                                         LW[l].kw, LW[l].kb, hc,
                                                         BtQK, biasQK, K, kshift[l], Np0);
        }
        dim3 gqk(grid_m, Np0 / 128);
        gemm128<<<gqk, 256, 0, stream>>>(Acur, BtQK, biasQK, QKVS, NN, Np0, K);
        alpha_kernel<<<(NE + 3) / 4, 256, 0, stream>>>(QKVS, src, dst, alphaBuf, NE, Np0, hc, C,
                                                       1.0f / sqrtf((float)C));
        // V|S weights (pad zero)
        {
            int tot = Np1 << kshift[l];
            prep2<<<(tot + 255) / 256, 256, 0, stream>>>(LW[l].vw, LW[l].vb, hc,
                                                         LW[l].sw, LW[l].sb, C,
                                                         BtVS, biasVS, K, kshift[l], Np1);
        }
        dim3 gvs(grid_m, Np1 / 128);
        gemm128<<<gvs, 256, 0, stream>>>(Acur, BtVS, biasVS, QKVS, NN, Np1, K);
        node_pass<<<NN, 256, 0, stream>>>(alphaBuf, QKVS, offs, eidx, src, hf, houth, C, hc, Np1);
        Acur = houth;
    }

    // pooling
    pool_init<<<(NG * 64 + 255) / 256, 256, 0, stream>>>(gm, gd, pooled);
    gate_kernel<<<(NN + 3) / 4, 256, 0, stream>>>(hf, gate_w, gate_b, batch, gbuf, gm, NN);
    gate_norm<<<(NN + 255) / 256, 256, 0, stream>>>(gbuf, gm, gd, batch, NN);
    pool_accum<<<(NN * 64 + 255) / 256, 256, 0, stream>>>(gbuf, gd, hf, batch, pooled, NN);
    final_fc<<<1, 512, 0, stream>>>(pooled, fc_w, fc_b, (float*)d_out);
}

// Round 3
// 835.993 us; speedup vs baseline: 1.4614x; 1.0695x over previous
//
#include <hip/hip_runtime.h>
#include <stdint.h>
#include <math.h>

#define NN 10000
#define NE 30000
#define NG 50
#define NH 8

typedef _Float16 f16;
typedef _Float16 f16x2 __attribute__((ext_vector_type(2)));
typedef _Float16 f16x4 __attribute__((ext_vector_type(4)));
typedef _Float16 f16x8 __attribute__((ext_vector_type(8)));
typedef float f32x4 __attribute__((ext_vector_type(4)));

// ---------------- helpers ----------------
__device__ inline void atomicMaxF(float* addr, float val) {
    if (val >= 0.0f) atomicMax((int*)addr, __float_as_int(val));
    else             atomicMin((unsigned int*)addr, __float_as_uint(val));
}

__device__ inline void async16(f16* l, const f16* g) {
    __builtin_amdgcn_global_load_lds((const __attribute__((address_space(1))) void*)g,
                                     (__attribute__((address_space(3))) void*)l, 16, 0, 0);
}

// ---------------- CSR build ----------------
__global__ void hist_kernel(const int* __restrict__ dst, int* __restrict__ deg, int E) {
    int e = blockIdx.x * blockDim.x + threadIdx.x;
    if (e < E) atomicAdd(&deg[dst[e]], 1);
}

__global__ __launch_bounds__(1024) void scan_kernel(const int* __restrict__ deg, int* __restrict__ offs, int n) {
    __shared__ int tmp[1024];
    __shared__ int carry;
    if (threadIdx.x == 0) { carry = 0; offs[0] = 0; }
    __syncthreads();
    for (int base = 0; base < n; base += 1024) {
        int i = base + (int)threadIdx.x;
        int v = (i < n) ? deg[i] : 0;
        tmp[threadIdx.x] = v;
        __syncthreads();
        for (int d = 1; d < 1024; d <<= 1) {
            int t = 0;
            if ((int)threadIdx.x >= d) t = tmp[threadIdx.x - d];
            __syncthreads();
            if ((int)threadIdx.x >= d) tmp[threadIdx.x] += t;
            __syncthreads();
        }
        if (i < n) offs[i + 1] = carry + tmp[threadIdx.x];
        __syncthreads();
        if (threadIdx.x == 0) carry += tmp[1023];
        __syncthreads();
    }
}

__global__ void copy_int(const int* __restrict__ a, int* __restrict__ b, int n) {
    int i = blockIdx.x * blockDim.x + threadIdx.x;
    if (i < n) b[i] = a[i];
}

__global__ void scatter_kernel(const int* __restrict__ dst, int* __restrict__ cursor,
                               int* __restrict__ eidx, int E) {
    int e = blockIdx.x * blockDim.x + threadIdx.x;
    if (e < E) {
        int p = atomicAdd(&cursor[dst[e]], 1);
        eidx[p] = e;
    }
}

// ---------------- conversions / weight prep ----------------
__global__ void cvt_f16_kernel(const float* __restrict__ in, f16* __restrict__ out, int n) {
    int i = blockIdx.x * blockDim.x + threadIdx.x;
    if (i < n) out[i] = (f16)in[i];
}

// Build Bt [Ntot][K] f16 (transposed, concatenated W0|W1|zero-pad) + bias [Ntot] f32.
__global__ void prep2(const float* __restrict__ W0, const float* __restrict__ b0, int n0,
                      const float* __restrict__ W1, const float* __restrict__ b1, int n1,
                      f16* __restrict__ Bt, float* __restrict__ bias,
                      int K, int kshift, int Ntot) {
    int tid = blockIdx.x * blockDim.x + threadIdx.x;
    if (tid >= (Ntot << kshift)) return;
    int n = tid >> kshift;
    int k = tid & (K - 1);
    float w = 0.0f;
    if (n < n0) w = W0[(size_t)k * n0 + n];
    else if (n < n0 + n1) w = W1[(size_t)k * n1 + (n - n0)];
    Bt[tid] = (f16)w;
    if (k == 0) bias[n] = (n < n0) ? b0[n] : ((n < n0 + n1) ? b1[n - n0] : 0.0f);
}

// ---------------- GEMM: C[M,Np] = A[M,K] @ Bt[Np,K]^T + bias, f16 out ----------------
// 128x128 block tile, BK=32, global_load_lds staging with XOR-swizzled k-chunks
// (kills ds_read_b128 bank conflicts), swapped-operand MFMA, LDS-staged epilogue
// producing 16B/lane full-line coalesced stores (kills TCC write-allocate fetches).
__global__ __launch_bounds__(256) void gemm128(const f16* __restrict__ A, const f16* __restrict__ Bt,
                                               const float* __restrict__ bias, f16* __restrict__ C,
                                               int M, int Np, int K) {
    __shared__ f16 sA[128 * 32];
    __shared__ f16 sB[128 * 32];
    __shared__ f16 sC[64 * 136];   // 64 rows x 128 cols, pad 8 f16
    const int tid  = threadIdx.x;
    const int lane = tid & 63;
    const int wave = tid >> 6;
    const int l16  = lane & 15;
    const int quad = lane >> 4;
    const int rm   = blockIdx.x * 128;
    const int cn   = blockIdx.y * 128;
    const int wrow = (wave >> 1) * 64;
    const int wcol = (wave & 1) * 64;

    // staging: thread handles rows rA, rA+64; k-chunk swizzled by (row>>1)&3
    const int rA  = tid >> 2;
    const int sw  = (rA >> 1) & 3;
    const int kc  = ((tid & 3) ^ sw) << 3;
    int rowA0 = rm + rA;       if (rowA0 >= M) rowA0 = M - 1;
    int rowA1 = rm + rA + 64;  if (rowA1 >= M) rowA1 = M - 1;
    const f16* gA0 = A + (size_t)rowA0 * K + kc;
    const f16* gA1 = A + (size_t)rowA1 * K + kc;
    const f16* gB0 = Bt + (size_t)(cn + rA) * K + kc;
    const f16* gB1 = Bt + (size_t)(cn + rA + 64) * K + kc;
    f16* lA0 = sA + tid * 8;
    f16* lA1 = sA + tid * 8 + 2048;
    f16* lB0 = sB + tid * 8;
    f16* lB1 = sB + tid * 8 + 2048;

    // fragment read: entry (row, c) holds k-chunk c ^ ((row>>1)&3)
    const int swf = (l16 >> 1) & 3;
    const f16* rdA = sA + (wrow + l16) * 32 + ((quad ^ swf) << 3);
    const f16* rdB = sB + (wcol + l16) * 32 + ((quad ^ swf) << 3);

    f32x4 acc[4][4] = {};

    for (int k0 = 0; k0 < K; k0 += 32) {
        __syncthreads();
        async16(lA0, gA0); async16(lA1, gA1);
        async16(lB0, gB0); async16(lB1, gB1);
        gA0 += 32; gA1 += 32; gB0 += 32; gB1 += 32;
        __syncthreads();   // drains vmcnt -> staging complete
        f16x8 av[4], bv[4];
#pragma unroll
        for (int i = 0; i < 4; ++i) av[i] = *(const f16x8*)(rdA + i * 512);
#pragma unroll
        for (int j = 0; j < 4; ++j) bv[j] = *(const f16x8*)(rdB + j * 512);
#pragma unroll
        for (int i = 0; i < 4; ++i)
#pragma unroll
            for (int j = 0; j < 4; ++j)
                // swapped operands: D rows = A-rows (l16+16i), cols = B-rows (quad*4+r+16j)
                acc[i][j] = __builtin_amdgcn_mfma_f32_16x16x32_f16(bv[j], av[i], acc[i][j], 0, 0, 0);
    }
    __syncthreads();

    // epilogue: 2 rounds of 64 rows, staged through sC, stored as full 128B lines
    for (int round = 0; round < 2; ++round) {
        if ((wave >> 1) == round) {
#pragma unroll
            for (int j = 0; j < 4; ++j) {
                const int cb = wcol + j * 16 + quad * 4;   // col within 128
                const float4 bb = *(const float4*)(bias + cn + cb);
#pragma unroll
                for (int i = 0; i < 4; ++i) {
                    const int r = i * 16 + l16;            // row within 64
                    f16x4 o;
                    o[0] = (f16)(acc[i][j][0] + bb.x);
                    o[1] = (f16)(acc[i][j][1] + bb.y);
                    o[2] = (f16)(acc[i][j][2] + bb.z);
                    o[3] = (f16)(acc[i][j][3] + bb.w);
                    *(f16x4*)(sC + r * 136 + cb) = o;
                }
            }
        }
        __syncthreads();
#pragma unroll
        for (int it = 0; it < 4; ++it) {
            const int r = it * 16 + (tid >> 4);
            const int ch = tid & 15;
            const int grow = rm + round * 64 + r;
            if (grow < M) {
                f16x8 v = *(const f16x8*)(sC + r * 136 + ch * 8);
                *(f16x8*)(C + (size_t)grow * Np + cn + ch * 8) = v;
            }
        }
        __syncthreads();
    }
}

// ---------------- edge attention logits ----------------
__global__ __launch_bounds__(256) void alpha_kernel(const f16* __restrict__ QK,
                                                    const int* __restrict__ src, const int* __restrict__ dst,
                                                    float* __restrict__ alpha, int E, int stride, int koff,
                                                    int C, float scale) {
    const int wid = blockIdx.x * 4 + ((int)threadIdx.x >> 6);
    const int lane = threadIdx.x & 63;
    if (wid >= E) return;
    const int s = src[wid], d = dst[wid];
    const f16x8* Q8 = (const f16x8*)(QK + (size_t)d * stride);
    const f16x8* K8 = (const f16x8*)(QK + (size_t)s * stride + koff);
    const int cph = C >> 3;   // 16B chunks per head
    for (int h = 0; h < NH; ++h) {
        float acc = 0.0f;
        for (int c = lane; c < cph; c += 64) {
            f16x8 qv = Q8[h * cph + c];
            f16x8 kv = K8[h * cph + c];
#pragma unroll
            for (int t = 0; t < 8; ++t) acc += (float)qv[t] * (float)kv[t];
        }
#pragma unroll
        for (int o = 32; o > 0; o >>= 1) acc += __shfl_down(acc, o, 64);
        if (lane == 0) alpha[(size_t)wid * NH + h] = acc * scale;
    }
}

// ---------------- per-node softmax + aggregation + skip + ELU ----------------
__global__ __launch_bounds__(256) void node_pass(const float* __restrict__ alpha, const f16* __restrict__ VS,
                                                 const int* __restrict__ offs, const int* __restrict__ eidx,
                                                 const int* __restrict__ srcArr,
                                                 float* __restrict__ hout, f16* __restrict__ houth,
                                                 int C, int hc, int Np) {
    const int n = blockIdx.x;
    const int e0 = offs[n];
    int d = offs[n + 1] - e0;
    if (d > 256) d = 256;

    __shared__ float sew[256 * NH];
    __shared__ int sed[256];
    const int tid = threadIdx.x;

    // coalesced gather of alpha rows + src ids into LDS
    for (int i = tid; i < d * NH; i += 256) {
        int e = i >> 3, h = i & 7;
        sew[e * NH + h] = alpha[(size_t)eidx[e0 + e] * NH + h];
    }
    for (int e = tid; e < d; e += 256) sed[e] = srcArr[eidx[e0 + e]];
    __syncthreads();

    if (tid < NH) {
        const int h = tid;
        float m = -3.0e38f;
        for (int e = 0; e < d; ++e) m = fmaxf(m, sew[e * NH + h]);
        float den = 0.0f;
        for (int e = 0; e < d; ++e) {
            float ex = __expf(sew[e * NH + h] - m);
            sew[e * NH + h] = ex;
            den += ex;
        }
        float inv = 1.0f / (fmaxf(den, 1e-16f) * (float)NH);
        for (int e = 0; e < d; ++e) sew[e * NH + h] *= inv;
    }
    __syncthreads();

    const int half = C >> 1;
    for (int cp = tid; cp < half; cp += 256) {
        const int c = cp * 2;
        float a0 = 0.0f, a1 = 0.0f;
        for (int e = 0; e < d; ++e) {
            const int s = sed[e];
            const unsigned int* vp = (const unsigned int*)(VS + (size_t)s * Np);
#pragma unroll
            for (int h = 0; h < NH; ++h) {
                float w = sew[e * NH + h];
                f16x2 vv = __builtin_bit_cast(f16x2, vp[((h * C) >> 1) + cp]);
                a0 += w * (float)vv.x;
                a1 += w * (float)vv.y;
            }
        }
        const f16* Sp = VS + (size_t)n * Np + hc;
        float o0 = a0 + (float)Sp[c];
        float o1 = a1 + (float)Sp[c + 1];
        o0 = o0 > 0.0f ? o0 : (__expf(o0) - 1.0f);
        o1 = o1 > 0.0f ? o1 : (__expf(o1) - 1.0f);
        hout[(size_t)n * C + c] = o0;
        hout[(size_t)n * C + c + 1] = o1;
        houth[(size_t)n * C + c] = (f16)o0;
        houth[(size_t)n * C + c + 1] = (f16)o1;
    }
}

// ---------------- pooling ----------------
__global__ void pool_init(float* __restrict__ gm, float* __restrict__ gd, float* __restrict__ pooled) {
    int i = blockIdx.x * blockDim.x + threadIdx.x;
    if (i < NG * 64) pooled[i] = 0.0f;
    if (i < NG) { gm[i] = __int_as_float(0xff800000); gd[i] = 0.0f; }
}

__global__ __launch_bounds__(256) void gate_kernel(const float* __restrict__ h, const float* __restrict__ gw,
                                                   const float* __restrict__ gb, const int* __restrict__ batch,
                                                   float* __restrict__ g, float* __restrict__ gm, int N) {
    const int wid = blockIdx.x * 4 + ((int)threadIdx.x >> 6);
    const int lane = threadIdx.x & 63;
    if (wid >= N) return;
    float acc = h[(size_t)wid * 64 + lane] * gw[lane];
#pragma unroll
    for (int o = 32; o > 0; o >>= 1) acc += __shfl_down(acc, o, 64);
    if (lane == 0) {
        float gv = acc + gb[0];
        g[wid] = gv;
        atomicMaxF(&gm[batch[wid]], gv);
    }
}

__global__ void gate_norm(float* __restrict__ g, const float* __restrict__ gm, float* __restrict__ gd,
                          const int* __restrict__ batch, int N) {
    int n = blockIdx.x * blockDim.x + threadIdx.x;
    if (n < N) {
        int b = batch[n];
        float ge = __expf(g[n] - gm[b]);
        g[n] = ge;
        atomicAdd(&gd[b], ge);
    }
}

__global__ void pool_accum(const float* __restrict__ g, const float* __restrict__ gd,
                           const float* __restrict__ h, const int* __restrict__ batch,
                           float* __restrict__ pooled, int N) {
    int tid = blockIdx.x * blockDim.x + threadIdx.x;
    if (tid < N * 64) {
        int n = tid >> 6;
        int c = tid & 63;
        int b = batch[n];
        float w = g[n] / fmaxf(gd[b], 1e-16f);
        atomicAdd(&pooled[b * 64 + c], w * h[(size_t)n * 64 + c]);
    }
}

__global__ __launch_bounds__(512) void final_fc(const float* __restrict__ pooled, const float* __restrict__ fcw,
                                                const float* __restrict__ fcb, float* __restrict__ out) {
    int tid = threadIdx.x;
    if (tid < NG * 10) {
        int gi = tid / 10, o = tid - gi * 10;
        float acc = fcb[o];
#pragma unroll
        for (int c = 0; c < 64; ++c) acc += pooled[gi * 64 + c] * fcw[c * 10 + o];
        out[tid] = acc;
    }
}

// ---------------- host ----------------
extern "C" void kernel_launch(void* const* d_in, const int* in_sizes, int n_in,
                              void* d_out, int out_size, void* d_ws, size_t ws_size,
                              hipStream_t stream) {
    const float* x   = (const float*)d_in[0];
    const int* ei    = (const int*)d_in[1];
    const int* src   = ei;
    const int* dst   = ei + NE;
    const int* batch = (const int*)d_in[2];

    struct LayerW { int fin, C, hc; const float *qw,*qb,*kw,*kb,*vw,*vb,*sw,*sb; };
    LayerW LW[3];
    const int fins[3]   = {128, 512, 256};
    const int kshift[3] = {7, 9, 8};
    const int Cs[3]     = {512, 256, 64};
    const int NpVS[3]   = {4608, 2304, 640};  // hc + C padded to x128
    for (int l = 0; l < 3; ++l) {
        int b = 3 + 8 * l;
        LW[l].fin = fins[l]; LW[l].C = Cs[l]; LW[l].hc = Cs[l] * NH;
        LW[l].qw = (const float*)d_in[b + 0]; LW[l].qb = (const float*)d_in[b + 1];
        LW[l].kw = (const float*)d_in[b + 2]; LW[l].kb = (const float*)d_in[b + 3];
        LW[l].vw = (const float*)d_in[b + 4]; LW[l].vb = (const float*)d_in[b + 5];
        LW[l].sw = (const float*)d_in[b + 6]; LW[l].sb = (const float*)d_in[b + 7];
    }
    const float* gate_w = (const float*)d_in[27];
    const float* gate_b = (const float*)d_in[28];
    const float* fc_w   = (const float*)d_in[29];
    const float* fc_b   = (const float*)d_in[30];

    size_t off = 0;
    char* ws = (char*)d_ws;
    auto alloc = [&](size_t bytes) -> void* {
        void* p = ws + off;
        off = (off + bytes + 255) & ~(size_t)255;
        return p;
    };
    f16* BtQK   = (f16*)alloc((size_t)4096 * 512 * sizeof(f16));
    f16* BtVS   = (f16*)alloc((size_t)2304 * 512 * sizeof(f16));
    float* biasQK = (float*)alloc(8192 * sizeof(float));
    float* biasVS = (float*)alloc(4608 * sizeof(float));
    f16* QKVS   = (f16*)alloc((size_t)NN * 8192 * sizeof(f16));
    f16* xh     = (f16*)alloc((size_t)NN * 128 * sizeof(f16));
    f16* houth  = (f16*)alloc((size_t)NN * 512 * sizeof(f16));
    float* hf   = (float*)alloc((size_t)NN * 512 * sizeof(float));
    float* alphaBuf = (float*)alloc((size_t)NE * NH * sizeof(float));
    int* deg    = (int*)alloc(NN * sizeof(int));
    int* offs   = (int*)alloc((NN + 1) * sizeof(int));
    int* cursor = (int*)alloc(NN * sizeof(int));
    int* eidx   = (int*)alloc(NE * sizeof(int));
    float* gbuf = (float*)alloc(NN * sizeof(float));
    float* gm   = (float*)alloc(NG * sizeof(float));
    float* gd   = (float*)alloc(NG * sizeof(float));
    float* pooled = (float*)alloc(NG * 64 * sizeof(float));
    if (off > ws_size) return;

    // CSR build
    hipMemsetAsync(deg, 0, NN * sizeof(int), stream);
    hist_kernel<<<(NE + 255) / 256, 256, 0, stream>>>(dst, deg, NE);
    scan_kernel<<<1, 1024, 0, stream>>>(deg, offs, NN);
    copy_int<<<(NN + 255) / 256, 256, 0, stream>>>(offs, cursor, NN);
    scatter_kernel<<<(NE + 255) / 256, 256, 0, stream>>>(dst, cursor, eidx, NE);

    cvt_f16_kernel<<<(NN * 128 + 255) / 256, 256, 0, stream>>>(x, xh, NN * 128);

    const int grid_m = (NN + 127) / 128;  // 79
    const f16* Acur = xh;
    for (int l = 0; l < 3; ++l) {
        const int K = LW[l].fin, C = LW[l].C, hc = LW[l].hc;
        const int Np0 = 2 * hc, Np1 = NpVS[l];

        {
            int tot = Np0 << kshift[l];
            prep2<<<(tot + 255) / 256, 256, 0, stream>>>(LW[l].qw, LW[l].qb, hc,
                                                         LW[l].kw, LW[l].kb, hc,
                                                         BtQK, biasQK, K, kshift[l], Np0);
        }
        dim3 gqk(grid_m, Np0 / 128);
        gemm128<<<gqk, 256, 0, stream>>>(Acur, BtQK, biasQK, QKVS, NN, Np0, K);
        alpha_kernel<<<(NE + 3) / 4, 256, 0, stream>>>(QKVS, src, dst, alphaBuf, NE, Np0, hc, C,
                                                       1.0f / sqrtf((float)C));
        {
            int tot = Np1 << kshift[l];
            prep2<<<(tot + 255) / 256, 256, 0, stream>>>(LW[l].vw, LW[l].vb, hc,
                                                         LW[l].sw, LW[l].sb, C,
                                                         BtVS, biasVS, K, kshift[l], Np1);
        }
        dim3 gvs(grid_m, Np1 / 128);
        gemm128<<<gvs, 256, 0, stream>>>(Acur, BtVS, biasVS, QKVS, NN, Np1, K);
        node_pass<<<NN, 256, 0, stream>>>(alphaBuf, QKVS, offs, eidx, src, hf, houth, C, hc, Np1);
        Acur = houth;
    }

    pool_init<<<(NG * 64 + 255) / 256, 256, 0, stream>>>(gm, gd, pooled);
    gate_kernel<<<(NN + 3) / 4, 256, 0, stream>>>(hf, gate_w, gate_b, batch, gbuf, gm, NN);
    gate_norm<<<(NN + 255) / 256, 256, 0, stream>>>(gbuf, gm, gd, batch, NN);
    pool_accum<<<(NN * 64 + 255) / 256, 256, 0, stream>>>(gbuf, gd, hf, batch, pooled, NN);
    final_fc<<<1, 512, 0, stream>>>(pooled, fc_w, fc_b, (float*)d_out);
}

// Round 4
// 824.918 us; speedup vs baseline: 1.4811x; 1.0134x over previous
//
#include <hip/hip_runtime.h>
#include <stdint.h>
#include <math.h>

#define NN 10000
#define NE 30000
#define NG 50
#define NH 8

typedef _Float16 f16;
typedef _Float16 f16x2 __attribute__((ext_vector_type(2)));
typedef _Float16 f16x4 __attribute__((ext_vector_type(4)));
typedef _Float16 f16x8 __attribute__((ext_vector_type(8)));
typedef float f32x4 __attribute__((ext_vector_type(4)));

// ---------------- helpers ----------------
__device__ inline void atomicMaxF(float* addr, float val) {
    if (val >= 0.0f) atomicMax((int*)addr, __float_as_int(val));
    else             atomicMin((unsigned int*)addr, __float_as_uint(val));
}

__device__ inline void async16(f16* l, const f16* g) {
    __builtin_amdgcn_global_load_lds((const __attribute__((address_space(1))) void*)g,
                                     (__attribute__((address_space(3))) void*)l, 16, 0, 0);
}

// ---------------- CSR build ----------------
__global__ void hist_kernel(const int* __restrict__ dst, int* __restrict__ deg, int E) {
    int e = blockIdx.x * blockDim.x + threadIdx.x;
    if (e < E) atomicAdd(&deg[dst[e]], 1);
}

__global__ __launch_bounds__(1024) void scan_kernel(const int* __restrict__ deg, int* __restrict__ offs, int n) {
    __shared__ int tmp[1024];
    __shared__ int carry;
    if (threadIdx.x == 0) { carry = 0; offs[0] = 0; }
    __syncthreads();
    for (int base = 0; base < n; base += 1024) {
        int i = base + (int)threadIdx.x;
        int v = (i < n) ? deg[i] : 0;
        tmp[threadIdx.x] = v;
        __syncthreads();
        for (int d = 1; d < 1024; d <<= 1) {
            int t = 0;
            if ((int)threadIdx.x >= d) t = tmp[threadIdx.x - d];
            __syncthreads();
            if ((int)threadIdx.x >= d) tmp[threadIdx.x] += t;
            __syncthreads();
        }
        if (i < n) offs[i + 1] = carry + tmp[threadIdx.x];
        __syncthreads();
        if (threadIdx.x == 0) carry += tmp[1023];
        __syncthreads();
    }
}

__global__ void copy_int(const int* __restrict__ a, int* __restrict__ b, int n) {
    int i = blockIdx.x * blockDim.x + threadIdx.x;
    if (i < n) b[i] = a[i];
}

__global__ void scatter_kernel(const int* __restrict__ dst, int* __restrict__ cursor,
                               int* __restrict__ eidx, int E) {
    int e = blockIdx.x * blockDim.x + threadIdx.x;
    if (e < E) {
        int p = atomicAdd(&cursor[dst[e]], 1);
        eidx[p] = e;
    }
}

// ---------------- conversions / weight prep ----------------
__global__ void cvt_f16_kernel(const float* __restrict__ in, f16* __restrict__ out, int n) {
    int i = blockIdx.x * blockDim.x + threadIdx.x;
    if (i < n) out[i] = (f16)in[i];
}

// Build Bt [Ntot][K] f16 (transposed, concatenated W0|W1|zero-pad) + bias [Ntot] f32.
__global__ void prep2(const float* __restrict__ W0, const float* __restrict__ b0, int n0,
                      const float* __restrict__ W1, const float* __restrict__ b1, int n1,
                      f16* __restrict__ Bt, float* __restrict__ bias,
                      int K, int kshift, int Ntot) {
    int tid = blockIdx.x * blockDim.x + threadIdx.x;
    if (tid >= (Ntot << kshift)) return;
    int n = tid >> kshift;
    int k = tid & (K - 1);
    float w = 0.0f;
    if (n < n0) w = W0[(size_t)k * n0 + n];
    else if (n < n0 + n1) w = W1[(size_t)k * n1 + (n - n0)];
    Bt[tid] = (f16)w;
    if (k == 0) bias[n] = (n < n0) ? b0[n] : ((n < n0 + n1) ? b1[n - n0] : 0.0f);
}

// ---------------- GEMM: C[M,Np] = A[M,K] @ Bt[Np,K]^T + bias, f16 out ----------------
// 128x128 block tile, BK=32, double-buffered global_load_lds staging with
// XOR-swizzled k-chunks, swapped-operand MFMA, union LDS (epilogue sC reuses the
// staging buffers), LDS-staged epilogue -> full-line coalesced stores.
// Grid x must be padded so OOB blocks early-exit (XCD-stable A mapping).
__global__ __launch_bounds__(256) void gemm128(const f16* __restrict__ A, const f16* __restrict__ Bt,
                                               const float* __restrict__ bias, f16* __restrict__ C,
                                               int M, int Np, int K) {
    __shared__ f16 smem[16384];   // 32 KB: sA[2] @ 0,4096  sB[2] @ 8192,12288 ; epilogue sC (8704) unions
    const int rm = blockIdx.x * 128;
    if (rm >= M) return;          // padded grid column: whole block exits (no barriers executed)
    const int tid  = threadIdx.x;
    const int lane = tid & 63;
    const int wave = tid >> 6;
    const int l16  = lane & 15;
    const int quad = lane >> 4;
    const int cn   = blockIdx.y * 128;
    const int wrow = (wave >> 1) * 64;
    const int wcol = (wave & 1) * 64;

    // staging: thread handles rows rA, rA+64; k-chunk swizzled by (row>>1)&3
    const int rA  = tid >> 2;
    const int sw  = (rA >> 1) & 3;
    const int kc  = ((tid & 3) ^ sw) << 3;
    int rowA0 = rm + rA;       if (rowA0 >= M) rowA0 = M - 1;
    int rowA1 = rm + rA + 64;  if (rowA1 >= M) rowA1 = M - 1;
    const f16* gA0 = A + (size_t)rowA0 * K + kc;
    const f16* gA1 = A + (size_t)rowA1 * K + kc;
    const f16* gB0 = Bt + (size_t)(cn + rA) * K + kc;
    const f16* gB1 = Bt + (size_t)(cn + rA + 64) * K + kc;

    f16* stA[2] = { smem + tid * 8,        smem + 4096 + tid * 8 };
    f16* stB[2] = { smem + 8192 + tid * 8, smem + 12288 + tid * 8 };

    // fragment read: entry (row, c) holds k-chunk c ^ ((row>>1)&3)
    const int swf = (l16 >> 1) & 3;
    const f16* rdA[2] = { smem + (wrow + l16) * 32 + ((quad ^ swf) << 3),
                          smem + 4096 + (wrow + l16) * 32 + ((quad ^ swf) << 3) };
    const f16* rdB[2] = { smem + 8192 + (wcol + l16) * 32 + ((quad ^ swf) << 3),
                          smem + 12288 + (wcol + l16) * 32 + ((quad ^ swf) << 3) };

    f32x4 acc[4][4] = {};

    // prologue: stage k=0 into buffer 0
    async16(stA[0], gA0); async16(stA[0] + 2048, gA1);
    async16(stB[0], gB0); async16(stB[0] + 2048, gB1);
    gA0 += 32; gA1 += 32; gB0 += 32; gB1 += 32;

    int buf = 0;
    for (int k0 = 0; k0 < K; k0 += 32) {
        __syncthreads();   // waits staging of buf (vmcnt) + prior reads of other buf
        if (k0 + 32 < K) {
            const int nb = buf ^ 1;
            async16(stA[nb], gA0); async16(stA[nb] + 2048, gA1);
            async16(stB[nb], gB0); async16(stB[nb] + 2048, gB1);
            gA0 += 32; gA1 += 32; gB0 += 32; gB1 += 32;
        }
        f16x8 av[4], bv[4];
#pragma unroll
        for (int i = 0; i < 4; ++i) av[i] = *(const f16x8*)(rdA[buf] + i * 512);
#pragma unroll
        for (int j = 0; j < 4; ++j) bv[j] = *(const f16x8*)(rdB[buf] + j * 512);
#pragma unroll
        for (int i = 0; i < 4; ++i)
#pragma unroll
            for (int j = 0; j < 4; ++j)
                acc[i][j] = __builtin_amdgcn_mfma_f32_16x16x32_f16(bv[j], av[i], acc[i][j], 0, 0, 0);
        buf ^= 1;
    }
    __syncthreads();   // all ds_reads done before sC overwrites staging buffers

    // epilogue: 2 rounds of 64 rows, staged through sC (=smem), full 128B-line stores
    f16* sC = smem;
    for (int round = 0; round < 2; ++round) {
        if ((wave >> 1) == round) {
#pragma unroll
            for (int j = 0; j < 4; ++j) {
                const int cb = wcol + j * 16 + quad * 4;
                const float4 bb = *(const float4*)(bias + cn + cb);
#pragma unroll
                for (int i = 0; i < 4; ++i) {
                    const int r = i * 16 + l16;
                    f16x4 o;
                    o[0] = (f16)(acc[i][j][0] + bb.x);
                    o[1] = (f16)(acc[i][j][1] + bb.y);
                    o[2] = (f16)(acc[i][j][2] + bb.z);
                    o[3] = (f16)(acc[i][j][3] + bb.w);
                    *(f16x4*)(sC + r * 136 + cb) = o;
                }
            }
        }
        __syncthreads();
#pragma unroll
        for (int it = 0; it < 4; ++it) {
            const int r = it * 16 + (tid >> 4);
            const int ch = tid & 15;
            const int grow = rm + round * 64 + r;
            if (grow < M) {
                f16x8 v = *(const f16x8*)(sC + r * 136 + ch * 8);
                *(f16x8*)(C + (size_t)grow * Np + cn + ch * 8) = v;
            }
        }
        __syncthreads();
    }
}

// ---------------- edge attention logits ----------------
__global__ __launch_bounds__(256) void alpha_kernel(const f16* __restrict__ QK,
                                                    const int* __restrict__ src, const int* __restrict__ dst,
                                                    float* __restrict__ alpha, int E, int stride, int koff,
                                                    int C, float scale) {
    const int wid = blockIdx.x * 4 + ((int)threadIdx.x >> 6);
    const int lane = threadIdx.x & 63;
    if (wid >= E) return;
    const int s = src[wid], d = dst[wid];
    const f16x8* Q8 = (const f16x8*)(QK + (size_t)d * stride);
    const f16x8* K8 = (const f16x8*)(QK + (size_t)s * stride + koff);
    const int cph = C >> 3;
    for (int h = 0; h < NH; ++h) {
        float acc = 0.0f;
        for (int c = lane; c < cph; c += 64) {
            f16x8 qv = Q8[h * cph + c];
            f16x8 kv = K8[h * cph + c];
#pragma unroll
            for (int t = 0; t < 8; ++t) acc += (float)qv[t] * (float)kv[t];
        }
#pragma unroll
        for (int o = 32; o > 0; o >>= 1) acc += __shfl_down(acc, o, 64);
        if (lane == 0) alpha[(size_t)wid * NH + h] = acc * scale;
    }
}

// ---------------- per-node softmax + aggregation + skip + ELU ----------------
__global__ __launch_bounds__(256) void node_pass(const float* __restrict__ alpha, const f16* __restrict__ VS,
                                                 const int* __restrict__ offs, const int* __restrict__ eidx,
                                                 const int* __restrict__ srcArr,
                                                 float* __restrict__ hout, f16* __restrict__ houth,
                                                 int C, int hc, int Np) {
    const int n = blockIdx.x;
    const int e0 = offs[n];
    int d = offs[n + 1] - e0;
    if (d > 256) d = 256;

    __shared__ float sew[256 * NH];
    __shared__ int sed[256];
    const int tid = threadIdx.x;

    for (int i = tid; i < d * NH; i += 256) {
        int e = i >> 3, h = i & 7;
        sew[e * NH + h] = alpha[(size_t)eidx[e0 + e] * NH + h];
    }
    for (int e = tid; e < d; e += 256) sed[e] = srcArr[eidx[e0 + e]];
    __syncthreads();

    if (tid < NH) {
        const int h = tid;
        float m = -3.0e38f;
        for (int e = 0; e < d; ++e) m = fmaxf(m, sew[e * NH + h]);
        float den = 0.0f;
        for (int e = 0; e < d; ++e) {
            float ex = __expf(sew[e * NH + h] - m);
            sew[e * NH + h] = ex;
            den += ex;
        }
        float inv = 1.0f / (fmaxf(den, 1e-16f) * (float)NH);
        for (int e = 0; e < d; ++e) sew[e * NH + h] *= inv;
    }
    __syncthreads();

    const int half = C >> 1;
    for (int cp = tid; cp < half; cp += 256) {
        const int c = cp * 2;
        float a0 = 0.0f, a1 = 0.0f;
        for (int e = 0; e < d; ++e) {
            const int s = sed[e];
            const unsigned int* vp = (const unsigned int*)(VS + (size_t)s * Np);
#pragma unroll
            for (int h = 0; h < NH; ++h) {
                float w = sew[e * NH + h];
                f16x2 vv = __builtin_bit_cast(f16x2, vp[((h * C) >> 1) + cp]);
                a0 += w * (float)vv.x;
                a1 += w * (float)vv.y;
            }
        }
        const f16* Sp = VS + (size_t)n * Np + hc;
        float o0 = a0 + (float)Sp[c];
        float o1 = a1 + (float)Sp[c + 1];
        o0 = o0 > 0.0f ? o0 : (__expf(o0) - 1.0f);
        o1 = o1 > 0.0f ? o1 : (__expf(o1) - 1.0f);
        hout[(size_t)n * C + c] = o0;
        hout[(size_t)n * C + c + 1] = o1;
        houth[(size_t)n * C + c] = (f16)o0;
        houth[(size_t)n * C + c + 1] = (f16)o1;
    }
}

// ---------------- pooling ----------------
__global__ void pool_init(float* __restrict__ gm, float* __restrict__ gd, float* __restrict__ pooled) {
    int i = blockIdx.x * blockDim.x + threadIdx.x;
    if (i < NG * 64) pooled[i] = 0.0f;
    if (i < NG) { gm[i] = __int_as_float(0xff800000); gd[i] = 0.0f; }
}

__global__ __launch_bounds__(256) void gate_kernel(const float* __restrict__ h, const float* __restrict__ gw,
                                                   const float* __restrict__ gb, const int* __restrict__ batch,
                                                   float* __restrict__ g, float* __restrict__ gm, int N) {
    const int wid = blockIdx.x * 4 + ((int)threadIdx.x >> 6);
    const int lane = threadIdx.x & 63;
    if (wid >= N) return;
    float acc = h[(size_t)wid * 64 + lane] * gw[lane];
#pragma unroll
    for (int o = 32; o > 0; o >>= 1) acc += __shfl_down(acc, o, 64);
    if (lane == 0) {
        float gv = acc + gb[0];
        g[wid] = gv;
        atomicMaxF(&gm[batch[wid]], gv);
    }
}

__global__ void gate_norm(float* __restrict__ g, const float* __restrict__ gm, float* __restrict__ gd,
                          const int* __restrict__ batch, int N) {
    int n = blockIdx.x * blockDim.x + threadIdx.x;
    if (n < N) {
        int b = batch[n];
        float ge = __expf(g[n] - gm[b]);
        g[n] = ge;
        atomicAdd(&gd[b], ge);
    }
}

__global__ void pool_accum(const float* __restrict__ g, const float* __restrict__ gd,
                           const float* __restrict__ h, const int* __restrict__ batch,
                           float* __restrict__ pooled, int N) {
    int tid = blockIdx.x * blockDim.x + threadIdx.x;
    if (tid < N * 64) {
        int n = tid >> 6;
        int c = tid & 63;
        int b = batch[n];
        float w = g[n] / fmaxf(gd[b], 1e-16f);
        atomicAdd(&pooled[b * 64 + c], w * h[(size_t)n * 64 + c]);
    }
}

__global__ __launch_bounds__(512) void final_fc(const float* __restrict__ pooled, const float* __restrict__ fcw,
                                                const float* __restrict__ fcb, float* __restrict__ out) {
    int tid = threadIdx.x;
    if (tid < NG * 10) {
        int gi = tid / 10, o = tid - gi * 10;
        float acc = fcb[o];
#pragma unroll
        for (int c = 0; c < 64; ++c) acc += pooled[gi * 64 + c] * fcw[c * 10 + o];
        out[tid] = acc;
    }
}

// ---------------- host ----------------
extern "C" void kernel_launch(void* const* d_in, const int* in_sizes, int n_in,
                              void* d_out, int out_size, void* d_ws, size_t ws_size,
                              hipStream_t stream) {
    const float* x   = (const float*)d_in[0];
    const int* ei    = (const int*)d_in[1];
    const int* src   = ei;
    const int* dst   = ei + NE;
    const int* batch = (const int*)d_in[2];

    struct LayerW { int fin, C, hc; const float *qw,*qb,*kw,*kb,*vw,*vb,*sw,*sb; };
    LayerW LW[3];
    const int fins[3]   = {128, 512, 256};
    const int kshift[3] = {7, 9, 8};
    const int Cs[3]     = {512, 256, 64};
    const int NpVS[3]   = {4608, 2304, 640};  // hc + C padded to x128
    for (int l = 0; l < 3; ++l) {
        int b = 3 + 8 * l;
        LW[l].fin = fins[l]; LW[l].C = Cs[l]; LW[l].hc = Cs[l] * NH;
        LW[l].qw = (const float*)d_in[b + 0]; LW[l].qb = (const float*)d_in[b + 1];
        LW[l].kw = (const float*)d_in[b + 2]; LW[l].kb = (const float*)d_in[b + 3];
        LW[l].vw = (const float*)d_in[b + 4]; LW[l].vb = (const float*)d_in[b + 5];
        LW[l].sw = (const float*)d_in[b + 6]; LW[l].sb = (const float*)d_in[b + 7];
    }
    const float* gate_w = (const float*)d_in[27];
    const float* gate_b = (const float*)d_in[28];
    const float* fc_w   = (const float*)d_in[29];
    const float* fc_b   = (const float*)d_in[30];

    size_t off = 0;
    char* ws = (char*)d_ws;
    auto alloc = [&](size_t bytes) -> void* {
        void* p = ws + off;
        off = (off + bytes + 255) & ~(size_t)255;
        return p;
    };
    f16* BtQK   = (f16*)alloc((size_t)4096 * 512 * sizeof(f16));
    f16* BtVS   = (f16*)alloc((size_t)2304 * 512 * sizeof(f16));
    float* biasQK = (float*)alloc(8192 * sizeof(float));
    float* biasVS = (float*)alloc(4608 * sizeof(float));
    f16* QKVS   = (f16*)alloc((size_t)NN * 8192 * sizeof(f16));
    f16* xh     = (f16*)alloc((size_t)NN * 128 * sizeof(f16));
    f16* houth  = (f16*)alloc((size_t)NN * 512 * sizeof(f16));
    float* hf   = (float*)alloc((size_t)NN * 512 * sizeof(float));
    float* alphaBuf = (float*)alloc((size_t)NE * NH * sizeof(float));
    int* deg    = (int*)alloc(NN * sizeof(int));
    int* offs   = (int*)alloc((NN + 1) * sizeof(int));
    int* cursor = (int*)alloc(NN * sizeof(int));
    int* eidx   = (int*)alloc(NE * sizeof(int));
    float* gbuf = (float*)alloc(NN * sizeof(float));
    float* gm   = (float*)alloc(NG * sizeof(float));
    float* gd   = (float*)alloc(NG * sizeof(float));
    float* pooled = (float*)alloc(NG * 64 * sizeof(float));
    if (off > ws_size) return;

    // CSR build
    hipMemsetAsync(deg, 0, NN * sizeof(int), stream);
    hist_kernel<<<(NE + 255) / 256, 256, 0, stream>>>(dst, deg, NE);
    scan_kernel<<<1, 1024, 0, stream>>>(deg, offs, NN);
    copy_int<<<(NN + 255) / 256, 256, 0, stream>>>(offs, cursor, NN);
    scatter_kernel<<<(NE + 255) / 256, 256, 0, stream>>>(dst, cursor, eidx, NE);

    cvt_f16_kernel<<<(NN * 128 + 255) / 256, 256, 0, stream>>>(x, xh, NN * 128);

    // grid_m padded to a multiple of 8 so XCD = blockIdx.x % 8 is invariant
    // across y-passes -> each XCD's L2 retains its A-row slice (OOB blocks exit).
    const int grid_m = 80;
    const f16* Acur = xh;
    for (int l = 0; l < 3; ++l) {
        const int K = LW[l].fin, C = LW[l].C, hc = LW[l].hc;
        const int Np0 = 2 * hc, Np1 = NpVS[l];

        {
            int tot = Np0 << kshift[l];
            prep2<<<(tot + 255) / 256, 256, 0, stream>>>(LW[l].qw, LW[l].qb, hc,
                                                         LW[l].kw, LW[l].kb, hc,
                                                         BtQK, biasQK, K, kshift[l], Np0);
        }
        dim3 gqk(grid_m, Np0 / 128);
        gemm128<<<gqk, 256, 0, stream>>>(Acur, BtQK, biasQK, QKVS, NN, Np0, K);
        alpha_kernel<<<(NE + 3) / 4, 256, 0, stream>>>(QKVS, src, dst, alphaBuf, NE, Np0, hc, C,
                                                       1.0f / sqrtf((float)C));
        {
            int tot = Np1 << kshift[l];
            prep2<<<(tot + 255) / 256, 256, 0, stream>>>(LW[l].vw, LW[l].vb, hc,
                                                         LW[l].sw, LW[l].sb, C,
                                                         BtVS, biasVS, K, kshift[l], Np1);
        }
        dim3 gvs(grid_m, Np1 / 128);
        gemm128<<<gvs, 256, 0, stream>>>(Acur, BtVS, biasVS, QKVS, NN, Np1, K);
        node_pass<<<NN, 256, 0, stream>>>(alphaBuf, QKVS, offs, eidx, src, hf, houth, C, hc, Np1);
        Acur = houth;
    }

    pool_init<<<(NG * 64 + 255) / 256, 256, 0, stream>>>(gm, gd, pooled);
    gate_kernel<<<(NN + 3) / 4, 256, 0, stream>>>(hf, gate_w, gate_b, batch, gbuf, gm, NN);
    gate_norm<<<(NN + 255) / 256, 256, 0, stream>>>(gbuf, gm, gd, batch, NN);
    pool_accum<<<(NN * 64 + 255) / 256, 256, 0, stream>>>(gbuf, gd, hf, batch, pooled, NN);
    final_fc<<<1, 512, 0, stream>>>(pooled, fc_w, fc_b, (float*)d_out);
}